// Round 7
// baseline (344.418 us; speedup 1.0000x reference)
//
#include <hip/hip_runtime.h>
#include <hip/hip_bf16.h>
#include <cstdint>

#define E_ 32
#define H_ 1024
#define I_ 512
#define G_ 8
#define NSH_ 2
#define SCALE_ 2.5f
#define NROUTED (E_ * I_)            // 16384
#define PADCAP (16384 + E_ * 64)     // 18432, pad-to-64

typedef unsigned short u16;
using bf16x8_t = __attribute__((ext_vector_type(8))) __bf16;
using f32x4_t  = __attribute__((ext_vector_type(4))) float;

__device__ __forceinline__ u16 f2bf(float x) {
  union { float f; uint32_t u; } v; v.f = x;
  uint32_t u = v.u;
  uint32_t r = (u + 0x7fffu + ((u >> 16) & 1u)) >> 16;
  return (u16)r;
}
__device__ __forceinline__ float bf2f(u16 x) {
  union { uint32_t u; float f; } v; v.u = ((uint32_t)x) << 16; return v.f;
}

__device__ __forceinline__ void load_lds16(const void* g, void* l) {
  __builtin_amdgcn_global_load_lds(
      (const __attribute__((address_space(1))) unsigned int*)g,
      (__attribute__((address_space(3))) unsigned int*)l,
      16, 0, 0);
}

// ---------------- all f32 -> bf16 conversions, one grid-stride kernel -------
// weights layout in wbf (u16 elems): [wg | wu | wd | shg | shu | shd]
#define W4_WG  4194304L
#define W4_WU  8388608L
#define W4_WD  12582912L
#define W4_SHG 12845056L
#define W4_SHU 13107200L
#define W4_TOT 13369344L
__global__ void cvtw_kernel(const float* __restrict__ wg, const float* __restrict__ wu,
                            const float* __restrict__ wd, const float* __restrict__ shg,
                            const float* __restrict__ shu, const float* __restrict__ shd,
                            const float* __restrict__ hs, u16* __restrict__ wdst,
                            u16* __restrict__ hdst, long hs4) {
  long i = (long)blockIdx.x * blockDim.x + threadIdx.x;
  long stride = (long)gridDim.x * blockDim.x;
  long tot = W4_TOT + hs4;
  for (; i < tot; i += stride) {
    const float* s; long off; u16* d; long doff;
    if (i < hs4) { s = hs; off = i; d = hdst; doff = i; }
    else {
      long j = i - hs4;
      d = wdst; doff = j;
      if (j < W4_WG)       { s = wg;  off = j; }
      else if (j < W4_WU)  { s = wu;  off = j - W4_WG; }
      else if (j < W4_WD)  { s = wd;  off = j - W4_WU; }
      else if (j < W4_SHG) { s = shg; off = j - W4_WD; }
      else if (j < W4_SHU) { s = shu; off = j - W4_SHG; }
      else                 { s = shd; off = j - W4_SHU; }
    }
    float4 v = ((const float4*)s)[off];
    ushort4 o;
    o.x = f2bf(v.x); o.y = f2bf(v.y); o.z = f2bf(v.z); o.w = f2bf(v.w);
    ((ushort4*)d)[doff] = o;
  }
}

// ---------------- init ----------------
__global__ void init_kernel(int* __restrict__ counts, int* __restrict__ cursor,
                            int* __restrict__ tok_list, float* __restrict__ wt_list) {
  int i = blockIdx.x * blockDim.x + threadIdx.x;
  if (i < PADCAP) { tok_list[i] = 0; wt_list[i] = 0.f; }
  if (i < E_) { counts[i] = 0; cursor[i] = 0; }
}

// ---------------- router a: gw [E][H] -> gwT [H][E] ----------------
__global__ void gwt_kernel(const float* __restrict__ gw, float* __restrict__ gwT) {
  int i = blockIdx.x * blockDim.x + threadIdx.x;
  if (i >= H_ * E_) return;
  int k = i >> 5, e = i & 31;
  gwT[i] = gw[(long)e * H_ + k];
}

// ---------------- router b: logits (f32 exact) ----------
__global__ __launch_bounds__(256) void logits_kernel(
    const float* __restrict__ h, const float* __restrict__ gwT,
    float* __restrict__ logits) {
  __shared__ float sh[8][H_];
  const int tid = threadIdx.x;
  const int t0 = blockIdx.x * 8;
  #pragma unroll
  for (int c = tid; c < 8 * H_ / 4; c += 256) {
    int row = c / (H_ / 4), col = c % (H_ / 4);
    ((float4*)sh[row])[col] = ((const float4*)(h + (size_t)(t0 + row) * H_))[col];
  }
  __syncthreads();
  const int w = tid >> 6, l = tid & 63;
  const int e = l & 31, tl = w * 2 + (l >> 5);
  const float* hp = sh[tl];
  const float* wp = gwT + e;
  float acc = 0.f;
  #pragma unroll 8
  for (int k = 0; k < H_; ++k) acc += hp[k] * wp[(size_t)k * E_];
  logits[(size_t)(t0 + tl) * E_ + e] = acc;
}

// ---------------- router c: top-k (1 thread / token) ----------------
__global__ __launch_bounds__(256) void topk_kernel(
    const float* __restrict__ logits, const float* __restrict__ gb,
    int* __restrict__ idx8, float* __restrict__ wt8, int* __restrict__ counts) {
  __shared__ float s_sc[256][33];
  const int lt = threadIdx.x;
  const int t = blockIdx.x * 256 + lt;
  float sc[E_];
  #pragma unroll
  for (int e = 0; e < E_; ++e) {
    float lg = logits[(size_t)t * E_ + e];
    float sig = 1.f / (1.f + __expf(-lg));
    s_sc[lt][e] = sig;
    sc[e] = sig + gb[e];
  }
  float gs[G_];
  #pragma unroll
  for (int g = 0; g < G_; ++g) {
    float a = sc[g * 4], b = sc[g * 4 + 1], c = sc[g * 4 + 2], d = sc[g * 4 + 3];
    float hi1 = fmaxf(a, b), lo1 = fminf(a, b);
    float hi2 = fmaxf(c, d), lo2 = fminf(c, d);
    float m1 = fmaxf(hi1, hi2);
    float m2 = (hi1 >= hi2) ? fmaxf(lo1, hi2) : fmaxf(lo2, hi1);
    gs[g] = m1 + m2;
  }
  unsigned gm = 0;
  #pragma unroll
  for (int r = 0; r < 4; ++r) {
    float bv = -1e30f; int bi = 0;
    #pragma unroll
    for (int g = 0; g < G_; ++g)
      if (!(gm & (1u << g)) && gs[g] > bv) { bv = gs[g]; bi = g; }
    gm |= 1u << bi;
  }
  float msk[E_];
  #pragma unroll
  for (int e = 0; e < E_; ++e)
    msk[e] = ((gm >> (e >> 2)) & 1u) ? sc[e] : 0.f;
  unsigned um = 0; float wsum = 0.f;
  int idxs[8]; float wts[8];
  #pragma unroll
  for (int r = 0; r < 8; ++r) {
    float bv = -1e30f; int bi = 0;
    #pragma unroll
    for (int e = 0; e < E_; ++e)
      if (!(um & (1u << e)) && msk[e] > bv) { bv = msk[e]; bi = e; }
    um |= 1u << bi;
    idxs[r] = bi;
    float wv = s_sc[lt][bi];
    wts[r] = wv; wsum += wv;
  }
  float inv = SCALE_ / (wsum + 1e-20f);
  #pragma unroll
  for (int r = 0; r < 8; ++r) {
    idx8[(size_t)t * 8 + r] = idxs[r];
    wt8[(size_t)t * 8 + r] = wts[r] * inv;
    atomicAdd(&counts[idxs[r]], 1);
  }
}

// ---------------- scan (pad to 64) ----------------
__global__ void scan_kernel(const int* __restrict__ counts, int* __restrict__ offs) {
  if (threadIdx.x == 0 && blockIdx.x == 0) {
    int run = 0;
    for (int e = 0; e < E_; ++e) {
      offs[e] = run;
      run += ((counts[e] + 63) >> 6) << 6;
    }
    offs[E_] = run;
  }
}

// ---------------- fill ----------------
__global__ void fill_kernel(const int* __restrict__ idx8, const float* __restrict__ wt8,
                            const int* __restrict__ offs, int* __restrict__ cursor,
                            int* __restrict__ tok_list, float* __restrict__ wt_list,
                            int* __restrict__ pair_pos, int npair) {
  int i = blockIdx.x * blockDim.x + threadIdx.x;
  if (i >= npair) return;
  int e = idx8[i];
  int p = atomicAdd(&cursor[e], 1);
  int slot = offs[e] + p;
  tok_list[slot] = i >> 3;
  wt_list[slot] = wt8[i];
  pair_pos[i] = slot;
}

// ---------------- phase 1: gathered dual GEMM, dbuf + swizzle ----------------
// 256 thr = 4 waves (2x2). Tile 64 tok x 64 cols (dual gate+up). LDS 48KB dbuf.
__global__ __launch_bounds__(256, 3) void p1_kernel(
    const u16* __restrict__ hbf,
    const u16* __restrict__ bg, const u16* __restrict__ bu,
    const u16* __restrict__ bshg, const u16* __restrict__ bshu,
    const int* __restrict__ counts, const int* __restrict__ offs,
    const int* __restrict__ tok_list, const float* __restrict__ wt_list,
    u16* __restrict__ gu,          // [PADCAP][512]
    u16* __restrict__ gu_sh,       // [T][1024]
    int T) {
  const int z = blockIdx.z, tt = blockIdx.y, nb = blockIdx.x;
  const bool sh_e = (z == E_);
  if (!sh_e && nb >= 8) return;
  const int cnt = sh_e ? T : counts[z];
  if (tt * 64 >= cnt) return;
  const int off = sh_e ? 0 : offs[z];

  __shared__ u16 lsA[2][64 * 64];
  __shared__ u16 lsB0[2][64 * 64];
  __shared__ u16 lsB1[2][64 * 64];
  __shared__ int s_tok[64];
  __shared__ float s_wt[64];

  const int tid = threadIdx.x;
  if (tid < 64) {
    if (sh_e) { s_tok[tid] = tt * 64 + tid; s_wt[tid] = 1.0f; }
    else {
      int slot = off + tt * 64 + tid;
      s_tok[tid] = tok_list[slot];
      s_wt[tid] = wt_list[slot];
    }
  }
  __syncthreads();

  const u16* Bg = sh_e ? (bshg + (size_t)(nb * 64) * H_)
                       : (bg + ((size_t)z * I_ + nb * 64) * H_);
  const u16* Bu = sh_e ? (bshu + (size_t)(nb * 64) * H_)
                       : (bu + ((size_t)z * I_ + nb * 64) * H_);

  const int w = tid >> 6, l = tid & 63;
  const int wr = w >> 1, wc = w & 1;
  const int lr = l & 15, lh = l >> 4;
  const int sw = lr & 7;

  f32x4_t acc0[2][2], acc1[2][2];
  #pragma unroll
  for (int m = 0; m < 2; ++m)
    #pragma unroll
    for (int n = 0; n < 2; ++n) {
      acc0[m][n] = (f32x4_t){0.f, 0.f, 0.f, 0.f};
      acc1[m][n] = (f32x4_t){0.f, 0.f, 0.f, 0.f};
    }

  auto stage = [&](int b, int k0) {
    #pragma unroll
    for (int i = 0; i < 2; ++i) {
      int c = tid + 256 * i;
      int row = c >> 3, cb = c & 7;
      int scb = cb ^ (row & 7);
      load_lds16(hbf + (size_t)s_tok[row] * H_ + k0 + scb * 8, (char*)&lsA[b][0] + c * 16);
      load_lds16(Bg + (size_t)row * H_ + k0 + scb * 8, (char*)&lsB0[b][0] + c * 16);
      load_lds16(Bu + (size_t)row * H_ + k0 + scb * 8, (char*)&lsB1[b][0] + c * 16);
    }
  };
  auto compute = [&](int b) {
    #pragma unroll
    for (int kk = 0; kk < 64; kk += 32) {
      const int sb = kk >> 3;
      const int blk = ((sb + lh) ^ sw) << 3;
      bf16x8_t af[2], b0f[2], b1f[2];
      #pragma unroll
      for (int m = 0; m < 2; ++m)
        af[m] = *(const bf16x8_t*)(&lsA[b][0] + (wr * 32 + m * 16 + lr) * 64 + blk);
      #pragma unroll
      for (int n = 0; n < 2; ++n) {
        b0f[n] = *(const bf16x8_t*)(&lsB0[b][0] + (wc * 32 + n * 16 + lr) * 64 + blk);
        b1f[n] = *(const bf16x8_t*)(&lsB1[b][0] + (wc * 32 + n * 16 + lr) * 64 + blk);
      }
      #pragma unroll
      for (int m = 0; m < 2; ++m)
        #pragma unroll
        for (int n = 0; n < 2; ++n) {
          acc0[m][n] = __builtin_amdgcn_mfma_f32_16x16x32_bf16(af[m], b0f[n], acc0[m][n], 0, 0, 0);
          acc1[m][n] = __builtin_amdgcn_mfma_f32_16x16x32_bf16(af[m], b1f[n], acc1[m][n], 0, 0, 0);
        }
    }
  };

  stage(0, 0);
  __syncthreads();
  int cur = 0;
  #pragma unroll 1
  for (int s = 0; s < 16; ++s) {
    if (s < 15) stage(cur ^ 1, (s + 1) * 64);
    compute(cur);
    __syncthreads();
    cur ^= 1;
  }

  const int ldo = sh_e ? (I_ * NSH_) : I_;
  u16* outp = sh_e ? (gu_sh + (size_t)(tt * 64) * ldo + nb * 64)
                   : (gu + (size_t)(off + tt * 64) * ldo + nb * 64);
  #pragma unroll
  for (int m = 0; m < 2; ++m) {
    #pragma unroll
    for (int n = 0; n < 2; ++n) {
      int col = wc * 32 + n * 16 + lr;
      #pragma unroll
      for (int j = 0; j < 4; ++j) {
        int trow = wr * 32 + m * 16 + lh * 4 + j;
        float gv = acc0[m][n][j], uv = acc1[m][n][j];
        float sv = gv / (1.f + __expf(-gv));
        outp[(size_t)trow * ldo + col] = f2bf(sv * uv * s_wt[trow]);
      }
    }
  }
}

// ---------------- phase 2: gathered GEMM (down), dbuf + swizzle ----------------
// 256 thr = 4 waves (2x2). Tile 64 pairs x 128 H-cols. LDS 48KB dbuf.
__global__ __launch_bounds__(256, 3) void p2_kernel(
    const u16* __restrict__ gu, const u16* __restrict__ gu_sh,
    const u16* __restrict__ bd,    // [E][H][I] bf16
    const u16* __restrict__ bshd,  // [H][2I] bf16
    const int* __restrict__ counts, const int* __restrict__ offs,
    u16* __restrict__ part,        // [PADCAP][H]
    u16* __restrict__ part_sh,     // [T][H]
    int T) {
  const int z = blockIdx.z, tt = blockIdx.y, nb = blockIdx.x;  // nb: 8 x 128-col
  const bool sh_e = (z == E_);
  const int cnt = sh_e ? T : counts[z];
  if (tt * 64 >= cnt) return;

  __shared__ u16 lsA[2][64 * 64];
  __shared__ u16 lsB[2][128 * 64];

  const int tid = threadIdx.x;
  const int w = tid >> 6, l = tid & 63;
  const int wr = w >> 1, wc = w & 1;
  const int lr = l & 15, lh = l >> 4;
  const int sw = lr & 7;

  const int K = sh_e ? (I_ * NSH_) : I_;
  const int NT = K / 64;
  const u16* Ab = sh_e ? (gu_sh + (size_t)(tt * 64) * K)
                       : (gu + (size_t)(offs[z] + tt * 64) * K);
  const u16* Bb = sh_e ? (bshd + (size_t)(nb * 128) * K)
                       : (bd + (size_t)z * H_ * I_ + (size_t)(nb * 128) * K);
  u16* outp = sh_e ? (part_sh + (size_t)(tt * 64) * H_ + nb * 128)
                   : (part + (size_t)(offs[z] + tt * 64) * H_ + nb * 128);

  f32x4_t acc[2][4];
  #pragma unroll
  for (int m = 0; m < 2; ++m)
    #pragma unroll
    for (int n = 0; n < 4; ++n) acc[m][n] = (f32x4_t){0.f, 0.f, 0.f, 0.f};

  auto stage = [&](int b, int k0) {
    #pragma unroll
    for (int i = 0; i < 2; ++i) {
      int c = tid + 256 * i;
      int row = c >> 3, cb = c & 7;
      int scb = cb ^ (row & 7);
      load_lds16(Ab + (size_t)row * K + k0 + scb * 8, (char*)&lsA[b][0] + c * 16);
    }
    #pragma unroll
    for (int i = 0; i < 4; ++i) {
      int c = tid + 256 * i;
      int row = c >> 3, cb = c & 7;
      int scb = cb ^ (row & 7);
      load_lds16(Bb + (size_t)row * K + k0 + scb * 8, (char*)&lsB[b][0] + c * 16);
    }
  };
  auto compute = [&](int b) {
    #pragma unroll
    for (int kk = 0; kk < 64; kk += 32) {
      const int sb = kk >> 3;
      const int blk = ((sb + lh) ^ sw) << 3;
      bf16x8_t af[2], bf[4];
      #pragma unroll
      for (int m = 0; m < 2; ++m)
        af[m] = *(const bf16x8_t*)(&lsA[b][0] + (wr * 32 + m * 16 + lr) * 64 + blk);
      #pragma unroll
      for (int n = 0; n < 4; ++n)
        bf[n] = *(const bf16x8_t*)(&lsB[b][0] + (wc * 64 + n * 16 + lr) * 64 + blk);
      #pragma unroll
      for (int m = 0; m < 2; ++m)
        #pragma unroll
        for (int n = 0; n < 4; ++n)
          acc[m][n] = __builtin_amdgcn_mfma_f32_16x16x32_bf16(af[m], bf[n], acc[m][n], 0, 0, 0);
    }
  };

  stage(0, 0);
  __syncthreads();
  int cur = 0;
  #pragma unroll 1
  for (int s = 0; s < NT; ++s) {
    if (s < NT - 1) stage(cur ^ 1, (s + 1) * 64);
    compute(cur);
    __syncthreads();
    cur ^= 1;
  }

  #pragma unroll
  for (int m = 0; m < 2; ++m) {
    #pragma unroll
    for (int n = 0; n < 4; ++n) {
      int col = wc * 64 + n * 16 + lr;
      #pragma unroll
      for (int j = 0; j < 4; ++j) {
        int trow = wr * 32 + m * 16 + lh * 4 + j;
        outp[(size_t)trow * H_ + col] = f2bf(acc[m][n][j]);
      }
    }
  }
}

// ---------------- combine ----------------
__global__ void combine_kernel(const u16* __restrict__ part, const u16* __restrict__ part_sh,
                               const int* __restrict__ pair_pos, float* __restrict__ out) {
  int t = blockIdx.x;
  int h = threadIdx.x * 4;
  int pp[8];
  #pragma unroll
  for (int s = 0; s < 8; ++s) pp[s] = pair_pos[(long)t * 8 + s];
  ushort4 v = *(const ushort4*)(part_sh + (size_t)t * H_ + h);
  float a0 = bf2f(v.x), a1 = bf2f(v.y), a2 = bf2f(v.z), a3 = bf2f(v.w);
  #pragma unroll
  for (int s = 0; s < 8; ++s) {
    ushort4 u = *(const ushort4*)(part + (size_t)pp[s] * H_ + h);
    a0 += bf2f(u.x); a1 += bf2f(u.y); a2 += bf2f(u.z); a3 += bf2f(u.w);
  }
  float4 o = {a0, a1, a2, a3};
  *(float4*)(out + (size_t)t * H_ + h) = o;
}

extern "C" void kernel_launch(void* const* d_in, const int* in_sizes, int n_in,
                              void* d_out, int out_size, void* d_ws, size_t ws_size,
                              hipStream_t stream) {
  const float* hs  = (const float*)d_in[0];
  const float* gw  = (const float*)d_in[1];
  const float* gb  = (const float*)d_in[2];
  const float* wg  = (const float*)d_in[3];
  const float* wu  = (const float*)d_in[4];
  const float* wd  = (const float*)d_in[5];
  const float* shg = (const float*)d_in[6];
  const float* shu = (const float*)d_in[7];
  const float* shd = (const float*)d_in[8];
  float* out = (float*)d_out;

  const int T = in_sizes[0] / H_;  // 2048

  char* ws = (char*)d_ws;
  size_t off = 0;
  auto alloc = [&](size_t bytes) {
    char* p = ws + off;
    off += (bytes + 255) & ~(size_t)255;
    return p;
  };
  int*   counts   = (int*)alloc(E_ * 4);
  int*   cursor   = (int*)alloc(E_ * 4);
  int*   offsv    = (int*)alloc((E_ + 1) * 4);
  int*   idx8     = (int*)alloc((size_t)T * 8 * 4);
  float* wt8      = (float*)alloc((size_t)T * 8 * 4);
  int*   pair_pos = (int*)alloc((size_t)T * 8 * 4);
  int*   tok_list = (int*)alloc(PADCAP * 4);
  float* wt_list  = (float*)alloc(PADCAP * 4);
  float* gwT      = (float*)alloc((size_t)H_ * E_ * 4);
  float* logits   = (float*)alloc((size_t)T * E_ * 4);
  u16* hbf     = (u16*)alloc((size_t)T * H_ * 2);
  u16* wbf     = (u16*)alloc((size_t)W4_TOT * 4 * 2);
  u16* gu      = (u16*)alloc((size_t)PADCAP * I_ * 2);
  u16* gu_sh   = (u16*)alloc((size_t)T * I_ * NSH_ * 2);
  u16* part    = (u16*)alloc((size_t)PADCAP * H_ * 2);
  u16* part_sh = (u16*)alloc((size_t)T * H_ * 2);
  if (off > ws_size) return;

  u16* bg   = wbf;
  u16* bu   = wbf + (size_t)NROUTED * H_;
  u16* bd   = bu + (size_t)NROUTED * H_;
  u16* bshg = bd + (size_t)E_ * H_ * I_;
  u16* bshu = bshg + (size_t)I_ * NSH_ * H_;
  u16* bshd = bshu + (size_t)I_ * NSH_ * H_;

  hipLaunchKernelGGL(init_kernel, dim3((PADCAP + 255) / 256), dim3(256), 0, stream,
                     counts, cursor, tok_list, wt_list);

  // router (f32 exact)
  hipLaunchKernelGGL(gwt_kernel, dim3((H_ * E_ + 255) / 256), dim3(256), 0, stream, gw, gwT);
  hipLaunchKernelGGL(logits_kernel, dim3(T / 8), dim3(256), 0, stream, hs, gwT, logits);
  hipLaunchKernelGGL(topk_kernel, dim3(T / 256), dim3(256), 0, stream,
                     logits, gb, idx8, wt8, counts);
  hipLaunchKernelGGL(scan_kernel, dim3(1), dim3(64), 0, stream, counts, offsv);
  hipLaunchKernelGGL(fill_kernel, dim3((T * 8 + 255) / 256), dim3(256), 0, stream,
                     idx8, wt8, offsv, cursor, tok_list, wt_list, pair_pos, T * 8);

  // all conversions in one kernel (weights + hs)
  hipLaunchKernelGGL(cvtw_kernel, dim3(4096), dim3(256), 0, stream,
                     wg, wu, wd, shg, shu, shd, hs, wbf, hbf, (long)T * H_ / 4);

  hipLaunchKernelGGL(p1_kernel, dim3(16, T / 64, E_ + 1), dim3(256), 0, stream,
                     hbf, bg, bu, bshg, bshu, counts, offsv, tok_list, wt_list,
                     gu, gu_sh, T);

  hipLaunchKernelGGL(p2_kernel, dim3(8, T / 64, E_ + 1), dim3(256), 0, stream,
                     gu, gu_sh, bd, bshd, counts, offsv, part, part_sh, T);

  hipLaunchKernelGGL(combine_kernel, dim3(T), dim3(256), 0, stream,
                     part, part_sh, pair_pos, out);
}